// Round 2
// baseline (338.173 us; speedup 1.0000x reference)
//
#include <hip/hip_runtime.h>
#include <stdint.h>

#define M_ROWS 4096   // BATCH*SEQ
#define N_OUT  4096   // OUT_FEATURES
#define K_IN   4096   // IN_FEATURES
#define NNZ_N  1677722
#define CAP    640    // bucket capacity per row; mean 409.6, +11 sigma

typedef __attribute__((ext_vector_type(8))) short  bf16x8_t;  // 8 bf16 in 4 VGPRs
typedef __attribute__((ext_vector_type(4))) float  f32x4_t;

// ---------- fp32 -> bf16 (RNE) ----------
__device__ __forceinline__ unsigned short f2bf(float f) {
    union { float f; uint32_t u; } v; v.f = f;
    uint32_t u = v.u;
    u += 0x7FFFu + ((u >> 16) & 1u);   // round-to-nearest-even
    return (unsigned short)(u >> 16);
}

// ---------- K1: convert x -> bf16 (8 elems/thread) + zero counter region ----------
__global__ void convert_x_zero_cnt(const float4* __restrict__ x,
                                   uint4* __restrict__ xo,
                                   uint4* __restrict__ cntz) {
    int i = blockIdx.x * blockDim.x + threadIdx.x;  // exact-size grid (2.1M thr)
    if (i < 16384) {                                 // 256 KiB counter region
        uint4 z; z.x = z.y = z.z = z.w = 0u;
        cntz[i] = z;
    }
    float4 a = x[2 * i], b = x[2 * i + 1];
    uint4 o;
    o.x = (uint32_t)f2bf(a.x) | ((uint32_t)f2bf(a.y) << 16);
    o.y = (uint32_t)f2bf(a.z) | ((uint32_t)f2bf(a.w) << 16);
    o.z = (uint32_t)f2bf(b.x) | ((uint32_t)f2bf(b.y) << 16);
    o.w = (uint32_t)f2bf(b.z) | ((uint32_t)f2bf(b.w) << 16);
    xo[i] = o;
}

// ---------- K2: bin COO by row via hot-counter cursor ----------
// cnt is stride-16 (one counter per 64B line) so same-line TCC serialization is
// spread across 4096 lines. bucket entry = (col<<16) | bf16(data): plain 4B
// store to a unique slot -> no RMW, no line-miss-latency chain.
__global__ void bin_coo(const float* __restrict__ data,
                        const int* __restrict__ rows,
                        const int* __restrict__ cols,
                        uint32_t* __restrict__ cnt,
                        uint32_t* __restrict__ bucket, int nnz) {
    int i = blockIdx.x * blockDim.x + threadIdx.x;
    if (i >= nnz) return;
    int r = rows[i];
    uint32_t slot = atomicAdd(&cnt[r << 4], 1u);
    if (slot < CAP)   // statistically impossible overflow guard
        bucket[(size_t)r * CAP + slot] =
            ((uint32_t)cols[i] << 16) | (uint32_t)f2bf(data[i]);
}

// ---------- K3: per-row accumulate in LDS + fused bf16 convert + dense write ----------
// One block per W-row. Absorbs W-zeroing (writes every byte of the row).
__global__ __launch_bounds__(256) void accum_rows(const uint32_t* __restrict__ cnt,
                                                  const uint32_t* __restrict__ bucket,
                                                  unsigned short* __restrict__ W) {
    __shared__ float acc[K_IN];   // 16 KiB fp32 row accumulator
    const int r = blockIdx.x;
    const int t = threadIdx.x;

    float4* av = (float4*)acc;
#pragma unroll
    for (int j = t; j < K_IN / 4; j += 256) av[j] = (float4){0.f, 0.f, 0.f, 0.f};
    __syncthreads();

    uint32_t n = cnt[r << 4];
    if (n > CAP) n = CAP;
    const uint32_t* b = bucket + (size_t)r * CAP;
    for (uint32_t j = t; j < n; j += 256) {
        uint32_t e = b[j];
        union { uint32_t u; float f; } v; v.u = (e & 0xFFFFu) << 16;  // bf16->f32
        atomicAdd(&acc[e >> 16], v.f);   // ds_add_f32, trivial contention
    }
    __syncthreads();

    // write row r as bf16, 16B/thread coalesced
    uint4* wv = (uint4*)(W + (size_t)r * K_IN);
#pragma unroll
    for (int j = t; j < K_IN / 8; j += 256) {
        float4 a = av[2 * j], c = av[2 * j + 1];
        uint4 o;
        o.x = (uint32_t)f2bf(a.x) | ((uint32_t)f2bf(a.y) << 16);
        o.y = (uint32_t)f2bf(a.z) | ((uint32_t)f2bf(a.w) << 16);
        o.z = (uint32_t)f2bf(c.x) | ((uint32_t)f2bf(c.y) << 16);
        o.w = (uint32_t)f2bf(c.z) | ((uint32_t)f2bf(c.w) << 16);
        wv[j] = o;
    }
}

// ---------- async global->LDS helper (width 16B) ----------
__device__ __forceinline__ void async_ld16(const void* g, void* lds_wave_base) {
    __builtin_amdgcn_global_load_lds(
        (const __attribute__((address_space(1))) uint32_t*)g,
        (__attribute__((address_space(3))) uint32_t*)lds_wave_base,
        16, 0, 0);
}

// stage one 256x64 bf16 tile half (A or B) for K-tile kt into LDS slot:
// 4 x global_load_lds_dwordx4 per thread (512 thr x 16B x 4 = 32 KiB).
// LDS dest is linear (wave-uniform base + lane*16B); the XOR chunk swizzle
// (phys_chunk = chunk ^ (row&7)) is applied on the GLOBAL source address.
#define STAGE_M(gbase, lbase, kt, slot) do {                                   \
    const unsigned short* g_ = (gbase) + (kt) * 64;                            \
    unsigned short*       l_ = (lbase) + (slot) * 32768;                       \
    async_ld16(g_,                  l_);                                       \
    async_ld16(g_ + 1 * 64 * K_IN,  l_ + 4096);                                \
    async_ld16(g_ + 2 * 64 * K_IN,  l_ + 8192);                                \
    async_ld16(g_ + 3 * 64 * K_IN,  l_ + 12288);                               \
} while (0)

// ---------- C[M][N] = A[M][K] * B[N][K]^T, bf16 in, fp32 out ----------
// 256x256 block tile, BK=64, 512 threads = 8 waves (2M x 4N), wave tile 128x64.
// 2-slot LDS double buffer (128 KiB), 4-phase K-step with counted vmcnt(8).
// (unchanged from R1: 126 us, MfmaUtil 45%, bank conflicts 0)
__global__ __launch_bounds__(512, 2) void gemm_bt(const unsigned short* __restrict__ A,
                                                  const unsigned short* __restrict__ B,
                                                  float* __restrict__ C) {
    __shared__ __align__(16) unsigned short lds_[65536];  // 128 KiB: [A0|B0|A1|B1]

    const int t    = threadIdx.x;
    const int wave = t >> 6;
    const int lane = t & 63;
    const int wr   = wave >> 2;        // 0..1
    const int wc   = wave & 3;         // 0..3
    const int m0   = blockIdx.y * 256;
    const int n0   = blockIdx.x * 256;

    // staging source: LDS chunk lin = i*512 + t -> (row = lin>>3, phys = t&7),
    // logical chunk = (t&7) ^ (row&7)
    const int srow = t >> 3;
    const int sch  = ((t & 7) ^ (srow & 7)) * 8;
    const unsigned short* gA = A + (size_t)(m0 + srow) * K_IN + sch;
    const unsigned short* gB = B + (size_t)(n0 + srow) * K_IN + sch;
    unsigned short* lA = lds_ + wave * 512;           // wave-uniform dest bases
    unsigned short* lB = lds_ + 16384 + wave * 512;

    // ds_read fragment addressing: row&7 == lane&7, phys_chunk = c ^ (lane&7)
    const int l15  = lane & 15;
    const int aoff = (wr * 128 + l15) * 64;
    const int boff = (wc * 64  + l15) * 64;
    const int ck0  = (((lane >> 4)    ) ^ (lane & 7)) * 8;   // kk=0 (k 0..31)
    const int ck1  = (((lane >> 4) | 4) ^ (lane & 7)) * 8;   // kk=1 (k 32..63)

    f32x4_t acc[8][4];
#pragma unroll
    for (int i = 0; i < 8; ++i)
#pragma unroll
        for (int j = 0; j < 4; ++j) acc[i][j] = (f32x4_t){0.f, 0.f, 0.f, 0.f};

    bf16x8_t af[4][2], bf0[2][2], bf1[2][2];

    // prologue: K-tile0 -> slot0 (8 oldest loads), K-tile1 -> slot1
    STAGE_M(gA, lA, 0, 0); STAGE_M(gB, lB, 0, 0);
    STAGE_M(gA, lA, 1, 1); STAGE_M(gB, lB, 1, 1);
    asm volatile("s_waitcnt vmcnt(8)" ::: "memory");  // K-tile0 landed
    __builtin_amdgcn_s_barrier();

    for (int kt = 0; kt < 64; ++kt) {
        const unsigned short* pA = lds_ + (kt & 1) * 32768;
        const unsigned short* pB = pA + 16384;

        // ---------------- P1 ----------------
#pragma unroll
        for (int im = 0; im < 4; ++im) {
            af[im][0] = *(const bf16x8_t*)(pA + aoff + im * 1024 + ck0);
            af[im][1] = *(const bf16x8_t*)(pA + aoff + im * 1024 + ck1);
        }
#pragma unroll
        for (int jn = 0; jn < 2; ++jn) {
            bf0[jn][0] = *(const bf16x8_t*)(pB + boff + jn * 1024 + ck0);
            bf0[jn][1] = *(const bf16x8_t*)(pB + boff + jn * 1024 + ck1);
        }
        __builtin_amdgcn_s_barrier();
        asm volatile("s_waitcnt lgkmcnt(0)" ::: "memory");
        __builtin_amdgcn_s_setprio(1);
#pragma unroll
        for (int im = 0; im < 4; ++im)
#pragma unroll
            for (int jn = 0; jn < 2; ++jn)
#pragma unroll
                for (int kk = 0; kk < 2; ++kk)
                    acc[im][jn] = __builtin_amdgcn_mfma_f32_16x16x32_bf16(
                        af[im][kk], bf0[jn][kk], acc[im][jn], 0, 0, 0);
        __builtin_amdgcn_s_setprio(0);
        __builtin_amdgcn_s_barrier();

        // ---------------- P2 ----------------
#pragma unroll
        for (int jn = 0; jn < 2; ++jn) {
            bf1[jn][0] = *(const bf16x8_t*)(pB + boff + (2 + jn) * 1024 + ck0);
            bf1[jn][1] = *(const bf16x8_t*)(pB + boff + (2 + jn) * 1024 + ck1);
        }
        __builtin_amdgcn_s_barrier();
        asm volatile("s_waitcnt lgkmcnt(0)" ::: "memory");
        __builtin_amdgcn_s_setprio(1);
#pragma unroll
        for (int im = 0; im < 4; ++im)
#pragma unroll
            for (int jn = 0; jn < 2; ++jn)
#pragma unroll
                for (int kk = 0; kk < 2; ++kk)
                    acc[im][2 + jn] = __builtin_amdgcn_mfma_f32_16x16x32_bf16(
                        af[im][kk], bf1[jn][kk], acc[im][2 + jn], 0, 0, 0);
        __builtin_amdgcn_s_setprio(0);
        __builtin_amdgcn_s_barrier();

        // ---------------- P3 ----------------
        // slot-cur B fully read (P2 lgkm0 + barrier) -> safe to overwrite
        if (kt < 62) STAGE_M(gB, lB, kt + 2, (kt & 1));
#pragma unroll
        for (int im = 0; im < 4; ++im) {
            af[im][0] = *(const bf16x8_t*)(pA + aoff + (4 + im) * 1024 + ck0);
            af[im][1] = *(const bf16x8_t*)(pA + aoff + (4 + im) * 1024 + ck1);
        }
        __builtin_amdgcn_s_barrier();
        asm volatile("s_waitcnt lgkmcnt(0)" ::: "memory");
        __builtin_amdgcn_s_setprio(1);
#pragma unroll
        for (int im = 0; im < 4; ++im)
#pragma unroll
            for (int jn = 0; jn < 2; ++jn)
#pragma unroll
                for (int kk = 0; kk < 2; ++kk)
                    acc[4 + im][jn] = __builtin_amdgcn_mfma_f32_16x16x32_bf16(
                        af[im][kk], bf0[jn][kk], acc[4 + im][jn], 0, 0, 0);
        __builtin_amdgcn_s_setprio(0);
        __builtin_amdgcn_s_barrier();

        // ---------------- P4 ----------------
        // slot-cur A fully read (P3 lgkm0 + barrier) -> safe to overwrite
        if (kt < 62) STAGE_M(gA, lA, kt + 2, (kt & 1));
        __builtin_amdgcn_s_setprio(1);
#pragma unroll
        for (int im = 0; im < 4; ++im)
#pragma unroll
            for (int jn = 0; jn < 2; ++jn)
#pragma unroll
                for (int kk = 0; kk < 2; ++kk)
                    acc[4 + im][2 + jn] = __builtin_amdgcn_mfma_f32_16x16x32_bf16(
                        af[im][kk], bf1[jn][kk], acc[4 + im][2 + jn], 0, 0, 0);
        __builtin_amdgcn_s_setprio(0);
        if (kt < 62) {
            asm volatile("s_waitcnt vmcnt(8)" ::: "memory");  // K-tile kt+1 landed
        } else {
            asm volatile("s_waitcnt vmcnt(0)" ::: "memory");  // drain tail
        }
        __builtin_amdgcn_s_barrier();
    }

    // epilogue: C/D layout col = lane&15, row = (lane>>4)*4 + reg
    const int crow = m0 + wr * 128 + ((lane >> 4) << 2);
    const int ccol = n0 + wc * 64 + l15;
#pragma unroll
    for (int im = 0; im < 8; ++im)
#pragma unroll
        for (int jn = 0; jn < 4; ++jn)
#pragma unroll
            for (int r = 0; r < 4; ++r)
                C[(size_t)(crow + im * 16 + r) * N_OUT + ccol + jn * 16] =
                    acc[im][jn][r];
}

extern "C" void kernel_launch(void* const* d_in, const int* in_sizes, int n_in,
                              void* d_out, int out_size, void* d_ws, size_t ws_size,
                              hipStream_t stream) {
    const float* x    = (const float*)d_in[0];   // [2,2048,4096] fp32
    const float* data = (const float*)d_in[1];   // [NNZ]
    const int*   rows = (const int*)d_in[2];
    const int*   cols = (const int*)d_in[3];
    float*       out  = (float*)d_out;           // [2,2048,4096] fp32

    // workspace layout:
    //   W_bf16  32 MiB @ 0
    //   x_bf16  32 MiB @ 32M
    //   cnt    256 KiB @ 64M   (4096 counters, stride-16 ints = 1/line)
    //   bucket  10 MiB @ 65M   (4096 rows x CAP x 4B)
    unsigned short* W_bf16 = (unsigned short*)d_ws;
    unsigned short* x_bf16 = (unsigned short*)((char*)d_ws + (32u << 20));
    uint32_t*       cnt    = (uint32_t*)((char*)d_ws + (64u << 20));
    uint32_t*       bucket = (uint32_t*)((char*)d_ws + (65u << 20));

    // 1. convert x -> bf16 (16.7M elems, 8/thread) + zero counters
    convert_x_zero_cnt<<<(M_ROWS * K_IN) / (8 * 256), 256, 0, stream>>>(
        (const float4*)x, (uint4*)x_bf16, (uint4*)cnt);

    // 2. bin COO by row (hot-counter cursor + plain 4B bucket writes)
    bin_coo<<<(NNZ_N + 255) / 256, 256, 0, stream>>>(
        data, rows, cols, cnt, bucket, NNZ_N);

    // 3. per-row LDS accumulate -> dense bf16 W (absorbs W zeroing)
    accum_rows<<<N_OUT, 256, 0, stream>>>(cnt, bucket, W_bf16);

    // 4. y = x * W^T via bf16 MFMA GEMM (256x256 tile, 8-wave phase-split)
    dim3 grid(N_OUT / 256, M_ROWS / 256);  // 16 x 16 = 256 blocks = 1/CU
    gemm_bt<<<grid, 512, 0, stream>>>(x_bf16, W_bf16, out);
}

// Round 3
// 316.427 us; speedup vs baseline: 1.0687x; 1.0687x over previous
//
#include <hip/hip_runtime.h>
#include <stdint.h>

#define M_ROWS 4096   // BATCH*SEQ
#define N_OUT  4096   // OUT_FEATURES
#define K_IN   4096   // IN_FEATURES
#define NNZ_N  1677722
#define CAP    640    // bucket capacity per row; mean 409.6, +11 sigma
#define NB     256    // binning blocks
#define BCHUNK 6656   // ceil(NNZ / NB) rounded to 1024: 256*6656 >= NNZ

typedef __attribute__((ext_vector_type(8))) short  bf16x8_t;  // 8 bf16 in 4 VGPRs
typedef __attribute__((ext_vector_type(4))) float  f32x4_t;

// ---------- fp32 -> bf16 (RNE) ----------
__device__ __forceinline__ unsigned short f2bf(float f) {
    union { float f; uint32_t u; } v; v.f = f;
    uint32_t u = v.u;
    u += 0x7FFFu + ((u >> 16) & 1u);   // round-to-nearest-even
    return (unsigned short)(u >> 16);
}

// ---------- K1: convert x -> bf16 (8 elems/thread) ----------
__global__ void convert_x(const float4* __restrict__ x, uint4* __restrict__ xo) {
    int i = blockIdx.x * blockDim.x + threadIdx.x;  // exact-size grid
    float4 a = x[2 * i], b = x[2 * i + 1];
    uint4 o;
    o.x = (uint32_t)f2bf(a.x) | ((uint32_t)f2bf(a.y) << 16);
    o.y = (uint32_t)f2bf(a.z) | ((uint32_t)f2bf(a.w) << 16);
    o.z = (uint32_t)f2bf(b.x) | ((uint32_t)f2bf(b.y) << 16);
    o.w = (uint32_t)f2bf(b.z) | ((uint32_t)f2bf(b.w) << 16);
    xo[i] = o;
}

// ---------- K2a: per-block LDS histogram of COO rows (NO global atomics) ----------
__global__ __launch_bounds__(1024) void hist_coo(const int* __restrict__ rows,
                                                 uint32_t* __restrict__ Hist) {
    __shared__ uint32_t h[N_OUT];   // 16 KiB
    const int blk = blockIdx.x, t = threadIdx.x;
    for (int j = t; j < N_OUT; j += 1024) h[j] = 0;
    __syncthreads();
    const int start = blk * BCHUNK;
    const int end   = min(start + BCHUNK, NNZ_N);
    for (int i = start + t; i < end; i += 1024)
        atomicAdd(&h[rows[i]], 1u);                 // LDS atomic (on-CU)
    __syncthreads();
    for (int j = t; j < N_OUT; j += 1024)
        Hist[(size_t)blk * N_OUT + j] = h[j];       // coalesced
}

// ---------- K2b: exclusive scan over blocks, one wave per row-bin ----------
// In-place: Hist[blk][bin] becomes Base[blk][bin]; exact totals -> cnt[bin].
__global__ __launch_bounds__(256) void scan_hist(uint32_t* __restrict__ Hist,
                                                 uint32_t* __restrict__ cnt) {
    const int bin  = blockIdx.x * 4 + (threadIdx.x >> 6);
    const int lane = threadIdx.x & 63;
    uint32_t v[4], pre[4];
#pragma unroll
    for (int q = 0; q < 4; ++q)
        v[q] = Hist[(size_t)(lane * 4 + q) * N_OUT + bin];
    pre[0] = 0;
#pragma unroll
    for (int q = 1; q < 4; ++q) pre[q] = pre[q - 1] + v[q - 1];
    uint32_t tot = pre[3] + v[3];
    uint32_t x = tot;                                // wave exclusive scan
#pragma unroll
    for (int off = 1; off < 64; off <<= 1) {
        uint32_t y = __shfl_up(x, off);
        if (lane >= off) x += y;
    }
    uint32_t excl = x - tot;
#pragma unroll
    for (int q = 0; q < 4; ++q)
        Hist[(size_t)(lane * 4 + q) * N_OUT + bin] = excl + pre[q];
    if (lane == 63) cnt[bin] = excl + tot;
}

// ---------- K2c: place elements into row buckets via LDS cursors ----------
// cur[] starts at this block's exclusive base per row; slot sets across blocks
// are disjoint by construction -> plain 4B stores, zero global atomics.
__global__ __launch_bounds__(1024) void place_coo(const float* __restrict__ data,
                                                  const int* __restrict__ rows,
                                                  const int* __restrict__ cols,
                                                  const uint32_t* __restrict__ Base,
                                                  uint32_t* __restrict__ bucket) {
    __shared__ uint32_t cur[N_OUT];  // 16 KiB
    const int blk = blockIdx.x, t = threadIdx.x;
    for (int j = t; j < N_OUT; j += 1024)
        cur[j] = Base[(size_t)blk * N_OUT + j];
    __syncthreads();
    const int start = blk * BCHUNK;
    const int end   = min(start + BCHUNK, NNZ_N);
    for (int i = start + t; i < end; i += 1024) {
        int r = rows[i];
        uint32_t slot = atomicAdd(&cur[r], 1u);     // LDS atomic (on-CU)
        if (slot < CAP)                              // statistically impossible
            bucket[(size_t)r * CAP + slot] =
                ((uint32_t)cols[i] << 16) | (uint32_t)f2bf(data[i]);
    }
}

// ---------- K3: per-row accumulate in LDS + fused bf16 convert + dense write ----------
// One block per W-row. Absorbs W-zeroing (writes every byte of the row).
__global__ __launch_bounds__(256) void accum_rows(const uint32_t* __restrict__ cnt,
                                                  const uint32_t* __restrict__ bucket,
                                                  unsigned short* __restrict__ W) {
    __shared__ float acc[K_IN];   // 16 KiB fp32 row accumulator
    const int r = blockIdx.x;
    const int t = threadIdx.x;

    float4* av = (float4*)acc;
#pragma unroll
    for (int j = t; j < K_IN / 4; j += 256) av[j] = (float4){0.f, 0.f, 0.f, 0.f};
    __syncthreads();

    uint32_t n = cnt[r];
    if (n > CAP) n = CAP;
    const uint32_t* b = bucket + (size_t)r * CAP;
    for (uint32_t j = t; j < n; j += 256) {
        uint32_t e = b[j];
        union { uint32_t u; float f; } v; v.u = (e & 0xFFFFu) << 16;  // bf16->f32
        atomicAdd(&acc[e >> 16], v.f);   // ds_add_f32, trivial contention
    }
    __syncthreads();

    // write row r as bf16, 16B/thread coalesced
    uint4* wv = (uint4*)(W + (size_t)r * K_IN);
#pragma unroll
    for (int j = t; j < K_IN / 8; j += 256) {
        float4 a = av[2 * j], c = av[2 * j + 1];
        uint4 o;
        o.x = (uint32_t)f2bf(a.x) | ((uint32_t)f2bf(a.y) << 16);
        o.y = (uint32_t)f2bf(a.z) | ((uint32_t)f2bf(a.w) << 16);
        o.z = (uint32_t)f2bf(c.x) | ((uint32_t)f2bf(c.y) << 16);
        o.w = (uint32_t)f2bf(c.z) | ((uint32_t)f2bf(c.w) << 16);
        wv[j] = o;
    }
}

// ---------- async global->LDS helper (width 16B) ----------
__device__ __forceinline__ void async_ld16(const void* g, void* lds_wave_base) {
    __builtin_amdgcn_global_load_lds(
        (const __attribute__((address_space(1))) uint32_t*)g,
        (__attribute__((address_space(3))) uint32_t*)lds_wave_base,
        16, 0, 0);
}

// stage one 256x64 bf16 tile half (A or B) for K-tile kt into LDS slot:
// 4 x global_load_lds_dwordx4 per thread (512 thr x 16B x 4 = 32 KiB).
// LDS dest is linear (wave-uniform base + lane*16B); the XOR chunk swizzle
// (phys_chunk = chunk ^ (row&7)) is applied on the GLOBAL source address.
#define STAGE_M(gbase, lbase, kt, slot) do {                                   \
    const unsigned short* g_ = (gbase) + (kt) * 64;                            \
    unsigned short*       l_ = (lbase) + (slot) * 32768;                       \
    async_ld16(g_,                  l_);                                       \
    async_ld16(g_ + 1 * 64 * K_IN,  l_ + 4096);                                \
    async_ld16(g_ + 2 * 64 * K_IN,  l_ + 8192);                                \
    async_ld16(g_ + 3 * 64 * K_IN,  l_ + 12288);                               \
} while (0)

// ---------- C[M][N] = A[M][K] * B[N][K]^T, bf16 in, fp32 out ----------
// 256x256 block tile, BK=64, 512 threads = 8 waves (2M x 4N), wave tile 128x64.
// 2-slot LDS double buffer (128 KiB), 4-phase K-step with counted vmcnt(8).
// (unchanged from R1: 126 us, MfmaUtil 45%, bank conflicts 0)
__global__ __launch_bounds__(512, 2) void gemm_bt(const unsigned short* __restrict__ A,
                                                  const unsigned short* __restrict__ B,
                                                  float* __restrict__ C) {
    __shared__ __align__(16) unsigned short lds_[65536];  // 128 KiB: [A0|B0|A1|B1]

    const int t    = threadIdx.x;
    const int wave = t >> 6;
    const int lane = t & 63;
    const int wr   = wave >> 2;        // 0..1
    const int wc   = wave & 3;         // 0..3
    const int m0   = blockIdx.y * 256;
    const int n0   = blockIdx.x * 256;

    // staging source: LDS chunk lin = i*512 + t -> (row = lin>>3, phys = t&7),
    // logical chunk = (t&7) ^ (row&7)
    const int srow = t >> 3;
    const int sch  = ((t & 7) ^ (srow & 7)) * 8;
    const unsigned short* gA = A + (size_t)(m0 + srow) * K_IN + sch;
    const unsigned short* gB = B + (size_t)(n0 + srow) * K_IN + sch;
    unsigned short* lA = lds_ + wave * 512;           // wave-uniform dest bases
    unsigned short* lB = lds_ + 16384 + wave * 512;

    // ds_read fragment addressing: row&7 == lane&7, phys_chunk = c ^ (lane&7)
    const int l15  = lane & 15;
    const int aoff = (wr * 128 + l15) * 64;
    const int boff = (wc * 64  + l15) * 64;
    const int ck0  = (((lane >> 4)    ) ^ (lane & 7)) * 8;   // kk=0 (k 0..31)
    const int ck1  = (((lane >> 4) | 4) ^ (lane & 7)) * 8;   // kk=1 (k 32..63)

    f32x4_t acc[8][4];
#pragma unroll
    for (int i = 0; i < 8; ++i)
#pragma unroll
        for (int j = 0; j < 4; ++j) acc[i][j] = (f32x4_t){0.f, 0.f, 0.f, 0.f};

    bf16x8_t af[4][2], bf0[2][2], bf1[2][2];

    // prologue: K-tile0 -> slot0 (8 oldest loads), K-tile1 -> slot1
    STAGE_M(gA, lA, 0, 0); STAGE_M(gB, lB, 0, 0);
    STAGE_M(gA, lA, 1, 1); STAGE_M(gB, lB, 1, 1);
    asm volatile("s_waitcnt vmcnt(8)" ::: "memory");  // K-tile0 landed
    __builtin_amdgcn_s_barrier();

    for (int kt = 0; kt < 64; ++kt) {
        const unsigned short* pA = lds_ + (kt & 1) * 32768;
        const unsigned short* pB = pA + 16384;

        // ---------------- P1 ----------------
#pragma unroll
        for (int im = 0; im < 4; ++im) {
            af[im][0] = *(const bf16x8_t*)(pA + aoff + im * 1024 + ck0);
            af[im][1] = *(const bf16x8_t*)(pA + aoff + im * 1024 + ck1);
        }
#pragma unroll
        for (int jn = 0; jn < 2; ++jn) {
            bf0[jn][0] = *(const bf16x8_t*)(pB + boff + jn * 1024 + ck0);
            bf0[jn][1] = *(const bf16x8_t*)(pB + boff + jn * 1024 + ck1);
        }
        __builtin_amdgcn_s_barrier();
        asm volatile("s_waitcnt lgkmcnt(0)" ::: "memory");
        __builtin_amdgcn_s_setprio(1);
#pragma unroll
        for (int im = 0; im < 4; ++im)
#pragma unroll
            for (int jn = 0; jn < 2; ++jn)
#pragma unroll
                for (int kk = 0; kk < 2; ++kk)
                    acc[im][jn] = __builtin_amdgcn_mfma_f32_16x16x32_bf16(
                        af[im][kk], bf0[jn][kk], acc[im][jn], 0, 0, 0);
        __builtin_amdgcn_s_setprio(0);
        __builtin_amdgcn_s_barrier();

        // ---------------- P2 ----------------
#pragma unroll
        for (int jn = 0; jn < 2; ++jn) {
            bf1[jn][0] = *(const bf16x8_t*)(pB + boff + (2 + jn) * 1024 + ck0);
            bf1[jn][1] = *(const bf16x8_t*)(pB + boff + (2 + jn) * 1024 + ck1);
        }
        __builtin_amdgcn_s_barrier();
        asm volatile("s_waitcnt lgkmcnt(0)" ::: "memory");
        __builtin_amdgcn_s_setprio(1);
#pragma unroll
        for (int im = 0; im < 4; ++im)
#pragma unroll
            for (int jn = 0; jn < 2; ++jn)
#pragma unroll
                for (int kk = 0; kk < 2; ++kk)
                    acc[im][2 + jn] = __builtin_amdgcn_mfma_f32_16x16x32_bf16(
                        af[im][kk], bf1[jn][kk], acc[im][2 + jn], 0, 0, 0);
        __builtin_amdgcn_s_setprio(0);
        __builtin_amdgcn_s_barrier();

        // ---------------- P3 ----------------
        // slot-cur B fully read (P2 lgkm0 + barrier) -> safe to overwrite
        if (kt < 62) STAGE_M(gB, lB, kt + 2, (kt & 1));
#pragma unroll
        for (int im = 0; im < 4; ++im) {
            af[im][0] = *(const bf16x8_t*)(pA + aoff + (4 + im) * 1024 + ck0);
            af[im][1] = *(const bf16x8_t*)(pA + aoff + (4 + im) * 1024 + ck1);
        }
        __builtin_amdgcn_s_barrier();
        asm volatile("s_waitcnt lgkmcnt(0)" ::: "memory");
        __builtin_amdgcn_s_setprio(1);
#pragma unroll
        for (int im = 0; im < 4; ++im)
#pragma unroll
            for (int jn = 0; jn < 2; ++jn)
#pragma unroll
                for (int kk = 0; kk < 2; ++kk)
                    acc[4 + im][jn] = __builtin_amdgcn_mfma_f32_16x16x32_bf16(
                        af[im][kk], bf0[jn][kk], acc[4 + im][jn], 0, 0, 0);
        __builtin_amdgcn_s_setprio(0);
        __builtin_amdgcn_s_barrier();

        // ---------------- P4 ----------------
        // slot-cur A fully read (P3 lgkm0 + barrier) -> safe to overwrite
        if (kt < 62) STAGE_M(gA, lA, kt + 2, (kt & 1));
        __builtin_amdgcn_s_setprio(1);
#pragma unroll
        for (int im = 0; im < 4; ++im)
#pragma unroll
            for (int jn = 0; jn < 2; ++jn)
#pragma unroll
                for (int kk = 0; kk < 2; ++kk)
                    acc[4 + im][2 + jn] = __builtin_amdgcn_mfma_f32_16x16x32_bf16(
                        af[im][kk], bf1[jn][kk], acc[4 + im][2 + jn], 0, 0, 0);
        __builtin_amdgcn_s_setprio(0);
        if (kt < 62) {
            asm volatile("s_waitcnt vmcnt(8)" ::: "memory");  // K-tile kt+1 landed
        } else {
            asm volatile("s_waitcnt vmcnt(0)" ::: "memory");  // drain tail
        }
        __builtin_amdgcn_s_barrier();
    }

    // epilogue: C/D layout col = lane&15, row = (lane>>4)*4 + reg
    const int crow = m0 + wr * 128 + ((lane >> 4) << 2);
    const int ccol = n0 + wc * 64 + l15;
#pragma unroll
    for (int im = 0; im < 8; ++im)
#pragma unroll
        for (int jn = 0; jn < 4; ++jn)
#pragma unroll
            for (int r = 0; r < 4; ++r)
                C[(size_t)(crow + im * 16 + r) * N_OUT + ccol + jn * 16] =
                    acc[im][jn][r];
}

extern "C" void kernel_launch(void* const* d_in, const int* in_sizes, int n_in,
                              void* d_out, int out_size, void* d_ws, size_t ws_size,
                              hipStream_t stream) {
    const float* x    = (const float*)d_in[0];   // [2,2048,4096] fp32
    const float* data = (const float*)d_in[1];   // [NNZ]
    const int*   rows = (const int*)d_in[2];
    const int*   cols = (const int*)d_in[3];
    float*       out  = (float*)d_out;           // [2,2048,4096] fp32

    // workspace layout:
    //   W_bf16  32 MiB @ 0
    //   x_bf16  32 MiB @ 32M
    //   Hist     4 MiB @ 64M   (256 blocks x 4096 bins; becomes Base in-place)
    //   cnt     16 KiB @ 68M
    //   bucket  10 MiB @ 69M   (4096 rows x CAP x 4B)
    unsigned short* W_bf16 = (unsigned short*)d_ws;
    unsigned short* x_bf16 = (unsigned short*)((char*)d_ws + (32u << 20));
    uint32_t*       Hist   = (uint32_t*)((char*)d_ws + (64u << 20));
    uint32_t*       cnt    = (uint32_t*)((char*)d_ws + (68u << 20));
    uint32_t*       bucket = (uint32_t*)((char*)d_ws + (69u << 20));

    // 1. convert x -> bf16 (16.7M elems, 8/thread)
    convert_x<<<(M_ROWS * K_IN) / (8 * 256), 256, 0, stream>>>(
        (const float4*)x, (uint4*)x_bf16);

    // 2a. per-block LDS histogram of rows (no global atomics)
    hist_coo<<<NB, 1024, 0, stream>>>(rows, Hist);

    // 2b. exclusive scan over blocks per bin (wave per bin) + exact cnt
    scan_hist<<<N_OUT / 4, 256, 0, stream>>>(Hist, cnt);

    // 2c. place elements into row buckets (LDS cursors, plain stores)
    place_coo<<<NB, 1024, 0, stream>>>(data, rows, cols, Hist, bucket);

    // 3. per-row LDS accumulate -> dense bf16 W (absorbs W zeroing)
    accum_rows<<<N_OUT, 256, 0, stream>>>(cnt, bucket, W_bf16);

    // 4. y = x * W^T via bf16 MFMA GEMM (256x256 tile, 8-wave phase-split)
    dim3 grid(N_OUT / 256, M_ROWS / 256);  // 16 x 16 = 256 blocks = 1/CU
    gemm_bt<<<grid, 512, 0, stream>>>(x_bf16, W_bf16, out);
}

// Round 4
// 288.132 us; speedup vs baseline: 1.1737x; 1.0982x over previous
//
#include <hip/hip_runtime.h>
#include <stdint.h>

#define M_ROWS 4096   // BATCH*SEQ
#define N_OUT  4096   // OUT_FEATURES
#define K_IN   4096   // IN_FEATURES
#define NNZ_N  1677722
#define NBLK_A 128    // sort blocks
#define CHUNK_A 13108 // ceil(NNZ/NBLK_A); 128*13108 >= NNZ
#define NBINS  512    // row bins of 8 rows each

typedef __attribute__((ext_vector_type(8))) short  bf16x8_t;  // 8 bf16 in 4 VGPRs
typedef __attribute__((ext_vector_type(4))) float  f32x4_t;

// ---------- fp32 -> bf16 (RNE) ----------
__device__ __forceinline__ unsigned short f2bf(float f) {
    union { float f; uint32_t u; } v; v.f = f;
    uint32_t u = v.u;
    u += 0x7FFFu + ((u >> 16) & 1u);   // round-to-nearest-even
    return (unsigned short)(u >> 16);
}

// ---------- K1: convert x -> bf16 (8 elems/thread) ----------
__global__ void convert_x(const float4* __restrict__ x, uint4* __restrict__ xo) {
    int i = blockIdx.x * blockDim.x + threadIdx.x;  // exact-size grid
    float4 a = x[2 * i], b = x[2 * i + 1];
    uint4 o;
    o.x = (uint32_t)f2bf(a.x) | ((uint32_t)f2bf(a.y) << 16);
    o.y = (uint32_t)f2bf(a.z) | ((uint32_t)f2bf(a.w) << 16);
    o.z = (uint32_t)f2bf(b.x) | ((uint32_t)f2bf(b.y) << 16);
    o.w = (uint32_t)f2bf(b.z) | ((uint32_t)f2bf(b.w) << 16);
    xo[i] = o;
}

// ---------- K2: block-local counting sort of a COO chunk (LDS-only scatter) ----------
// Entry pack: bits 28-30 = row&7, 16-27 = col, 0-15 = bf16(val).
// Output: run[blk*CHUNK_A + j] sorted by bin (row>>3), coalesced write.
// Fbase transposed [bin][blk] (+ sentinel row NBINS holding nloc) for phase B.
__global__ __launch_bounds__(1024) void sort_local(const float* __restrict__ data,
                                                   const int* __restrict__ rows,
                                                   const int* __restrict__ cols,
                                                   uint32_t* __restrict__ run,
                                                   uint32_t* __restrict__ Fbase) {
    __shared__ uint32_t hist[NBINS];
    __shared__ uint32_t basev[NBINS];
    __shared__ uint32_t cur[NBINS];
    __shared__ uint32_t ebuf[CHUNK_A];   // 52.4 KiB sorted entries
    const int blk   = blockIdx.x, t = threadIdx.x;
    const int start = blk * CHUNK_A;
    const int end   = min(start + CHUNK_A, NNZ_N);
    const int nloc  = end - start;

    for (int j = t; j < NBINS; j += 1024) hist[j] = 0;
    __syncthreads();
    for (int i = start + t; i < end; i += 1024)
        atomicAdd(&hist[rows[i] >> 3], 1u);            // LDS atomic
    __syncthreads();

    if (t < 64) {   // wave 0: 512-bin exclusive scan (8 serial per lane + wave scan)
        uint32_t pre[8], loc = 0;
#pragma unroll
        for (int q = 0; q < 8; ++q) { pre[q] = loc; loc += hist[t * 8 + q]; }
        uint32_t x = loc;
#pragma unroll
        for (int off = 1; off < 64; off <<= 1) {
            uint32_t y = __shfl_up(x, off);
            if (t >= off) x += y;
        }
        uint32_t excl = x - loc;
#pragma unroll
        for (int q = 0; q < 8; ++q) {
            basev[t * 8 + q] = excl + pre[q];
            cur[t * 8 + q]   = excl + pre[q];
        }
    }
    __syncthreads();

    for (int i = start + t; i < end; i += 1024) {
        int r = rows[i];
        uint32_t slot = atomicAdd(&cur[r >> 3], 1u);   // LDS cursor
        ebuf[slot] = ((uint32_t)(r & 7) << 28) |
                     ((uint32_t)cols[i] << 16) | (uint32_t)f2bf(data[i]);
    }
    __syncthreads();

    for (int j = t; j < nloc; j += 1024)
        run[start + j] = ebuf[j];                      // coalesced stream-out
    if (t < NBINS) Fbase[(size_t)t * NBLK_A + blk] = basev[t];
    if (t == 0)    Fbase[(size_t)NBINS * NBLK_A + blk] = (uint32_t)nloc;
}

// ---------- K3: per-bin (8 rows) accumulate + fused bf16 convert + dense write ----------
// Block f gathers its 128 sorted segments, accumulates in 128 KiB LDS fp32,
// writes rows [f*8, f*8+8) coalesced (absorbs W zeroing).
__global__ __launch_bounds__(512) void accum_bins(const uint32_t* __restrict__ run,
                                                  const uint32_t* __restrict__ Fbase,
                                                  unsigned short* __restrict__ W) {
    __shared__ float    acc[8 * K_IN];     // 128 KiB
    __shared__ uint32_t segS[NBLK_A], segE[NBLK_A];
    const int f = blockIdx.x, t = threadIdx.x;

    float4* av = (float4*)acc;
    for (int j = t; j < 8 * K_IN / 4; j += 512) av[j] = (float4){0.f, 0.f, 0.f, 0.f};
    if (t < NBLK_A)                    segS[t]          = Fbase[(size_t)f * NBLK_A + t];
    else if (t < 2 * NBLK_A)           segE[t - NBLK_A] = Fbase[(size_t)(f + 1) * NBLK_A + (t - NBLK_A)];
    __syncthreads();

    const int wave = t >> 6, lane = t & 63;
    for (int blk = wave; blk < NBLK_A; blk += 8) {     // 8 waves split the 128 segments
        uint32_t s = segS[blk], e = segE[blk];
        const uint32_t* rp = run + (size_t)blk * CHUNK_A;
        for (uint32_t j = s + lane; j < e; j += 64) {
            uint32_t en = rp[j];
            union { uint32_t u; float fv; } v; v.u = (en & 0xFFFFu) << 16;  // bf16->f32
            atomicAdd(&acc[((en >> 28) & 7u) * K_IN + ((en >> 16) & 0xFFFu)], v.fv);
        }
    }
    __syncthreads();

    uint4* wv = (uint4*)(W + (size_t)f * 8 * K_IN);    // 8 rows, 64 KiB coalesced
    for (int j = t; j < 8 * K_IN / 8; j += 512) {
        float4 a = av[2 * j], c = av[2 * j + 1];
        uint4 o;
        o.x = (uint32_t)f2bf(a.x) | ((uint32_t)f2bf(a.y) << 16);
        o.y = (uint32_t)f2bf(a.z) | ((uint32_t)f2bf(a.w) << 16);
        o.z = (uint32_t)f2bf(c.x) | ((uint32_t)f2bf(c.y) << 16);
        o.w = (uint32_t)f2bf(c.z) | ((uint32_t)f2bf(c.w) << 16);
        wv[j] = o;
    }
}

// ---------- async global->LDS helper (width 16B) ----------
__device__ __forceinline__ void async_ld16(const void* g, void* lds_wave_base) {
    __builtin_amdgcn_global_load_lds(
        (const __attribute__((address_space(1))) uint32_t*)g,
        (__attribute__((address_space(3))) uint32_t*)lds_wave_base,
        16, 0, 0);
}

// stage one 256x64 bf16 tile half (A or B) for K-tile kt into LDS slot:
// 4 x global_load_lds_dwordx4 per thread (512 thr x 16B x 4 = 32 KiB).
// LDS dest is linear (wave-uniform base + lane*16B); the XOR chunk swizzle
// (phys_chunk = chunk ^ (row&7)) is applied on the GLOBAL source address.
#define STAGE_M(gbase, lbase, kt, slot) do {                                   \
    const unsigned short* g_ = (gbase) + (kt) * 64;                            \
    unsigned short*       l_ = (lbase) + (slot) * 32768;                       \
    async_ld16(g_,                  l_);                                       \
    async_ld16(g_ + 1 * 64 * K_IN,  l_ + 4096);                                \
    async_ld16(g_ + 2 * 64 * K_IN,  l_ + 8192);                                \
    async_ld16(g_ + 3 * 64 * K_IN,  l_ + 12288);                               \
} while (0)

// ---------- C[M][N] = A[M][K] * B[N][K]^T, bf16 in, fp32 out ----------
// 256x256 block tile, BK=64, 512 threads = 8 waves (2M x 4N), wave tile 128x64.
// 2-slot LDS double buffer (128 KiB), 4-phase K-step with counted vmcnt(8).
// (unchanged from R1: ~127 us, MfmaUtil 45%, bank conflicts 0)
__global__ __launch_bounds__(512, 2) void gemm_bt(const unsigned short* __restrict__ A,
                                                  const unsigned short* __restrict__ B,
                                                  float* __restrict__ C) {
    __shared__ __align__(16) unsigned short lds_[65536];  // 128 KiB: [A0|B0|A1|B1]

    const int t    = threadIdx.x;
    const int wave = t >> 6;
    const int lane = t & 63;
    const int wr   = wave >> 2;        // 0..1
    const int wc   = wave & 3;         // 0..3
    const int m0   = blockIdx.y * 256;
    const int n0   = blockIdx.x * 256;

    // staging source: LDS chunk lin = i*512 + t -> (row = lin>>3, phys = t&7),
    // logical chunk = (t&7) ^ (row&7)
    const int srow = t >> 3;
    const int sch  = ((t & 7) ^ (srow & 7)) * 8;
    const unsigned short* gA = A + (size_t)(m0 + srow) * K_IN + sch;
    const unsigned short* gB = B + (size_t)(n0 + srow) * K_IN + sch;
    unsigned short* lA = lds_ + wave * 512;           // wave-uniform dest bases
    unsigned short* lB = lds_ + 16384 + wave * 512;

    // ds_read fragment addressing: row&7 == lane&7, phys_chunk = c ^ (lane&7)
    const int l15  = lane & 15;
    const int aoff = (wr * 128 + l15) * 64;
    const int boff = (wc * 64  + l15) * 64;
    const int ck0  = (((lane >> 4)    ) ^ (lane & 7)) * 8;   // kk=0 (k 0..31)
    const int ck1  = (((lane >> 4) | 4) ^ (lane & 7)) * 8;   // kk=1 (k 32..63)

    f32x4_t acc[8][4];
#pragma unroll
    for (int i = 0; i < 8; ++i)
#pragma unroll
        for (int j = 0; j < 4; ++j) acc[i][j] = (f32x4_t){0.f, 0.f, 0.f, 0.f};

    bf16x8_t af[4][2], bf0[2][2], bf1[2][2];

    // prologue: K-tile0 -> slot0 (8 oldest loads), K-tile1 -> slot1
    STAGE_M(gA, lA, 0, 0); STAGE_M(gB, lB, 0, 0);
    STAGE_M(gA, lA, 1, 1); STAGE_M(gB, lB, 1, 1);
    asm volatile("s_waitcnt vmcnt(8)" ::: "memory");  // K-tile0 landed
    __builtin_amdgcn_s_barrier();

    for (int kt = 0; kt < 64; ++kt) {
        const unsigned short* pA = lds_ + (kt & 1) * 32768;
        const unsigned short* pB = pA + 16384;

        // ---------------- P1 ----------------
#pragma unroll
        for (int im = 0; im < 4; ++im) {
            af[im][0] = *(const bf16x8_t*)(pA + aoff + im * 1024 + ck0);
            af[im][1] = *(const bf16x8_t*)(pA + aoff + im * 1024 + ck1);
        }
#pragma unroll
        for (int jn = 0; jn < 2; ++jn) {
            bf0[jn][0] = *(const bf16x8_t*)(pB + boff + jn * 1024 + ck0);
            bf0[jn][1] = *(const bf16x8_t*)(pB + boff + jn * 1024 + ck1);
        }
        __builtin_amdgcn_s_barrier();
        asm volatile("s_waitcnt lgkmcnt(0)" ::: "memory");
        __builtin_amdgcn_s_setprio(1);
#pragma unroll
        for (int im = 0; im < 4; ++im)
#pragma unroll
            for (int jn = 0; jn < 2; ++jn)
#pragma unroll
                for (int kk = 0; kk < 2; ++kk)
                    acc[im][jn] = __builtin_amdgcn_mfma_f32_16x16x32_bf16(
                        af[im][kk], bf0[jn][kk], acc[im][jn], 0, 0, 0);
        __builtin_amdgcn_s_setprio(0);
        __builtin_amdgcn_s_barrier();

        // ---------------- P2 ----------------
#pragma unroll
        for (int jn = 0; jn < 2; ++jn) {
            bf1[jn][0] = *(const bf16x8_t*)(pB + boff + (2 + jn) * 1024 + ck0);
            bf1[jn][1] = *(const bf16x8_t*)(pB + boff + (2 + jn) * 1024 + ck1);
        }
        __builtin_amdgcn_s_barrier();
        asm volatile("s_waitcnt lgkmcnt(0)" ::: "memory");
        __builtin_amdgcn_s_setprio(1);
#pragma unroll
        for (int im = 0; im < 4; ++im)
#pragma unroll
            for (int jn = 0; jn < 2; ++jn)
#pragma unroll
                for (int kk = 0; kk < 2; ++kk)
                    acc[im][2 + jn] = __builtin_amdgcn_mfma_f32_16x16x32_bf16(
                        af[im][kk], bf1[jn][kk], acc[im][2 + jn], 0, 0, 0);
        __builtin_amdgcn_s_setprio(0);
        __builtin_amdgcn_s_barrier();

        // ---------------- P3 ----------------
        // slot-cur B fully read (P2 lgkm0 + barrier) -> safe to overwrite
        if (kt < 62) STAGE_M(gB, lB, kt + 2, (kt & 1));
#pragma unroll
        for (int im = 0; im < 4; ++im) {
            af[im][0] = *(const bf16x8_t*)(pA + aoff + (4 + im) * 1024 + ck0);
            af[im][1] = *(const bf16x8_t*)(pA + aoff + (4 + im) * 1024 + ck1);
        }
        __builtin_amdgcn_s_barrier();
        asm volatile("s_waitcnt lgkmcnt(0)" ::: "memory");
        __builtin_amdgcn_s_setprio(1);
#pragma unroll
        for (int im = 0; im < 4; ++im)
#pragma unroll
            for (int jn = 0; jn < 2; ++jn)
#pragma unroll
                for (int kk = 0; kk < 2; ++kk)
                    acc[4 + im][jn] = __builtin_amdgcn_mfma_f32_16x16x32_bf16(
                        af[im][kk], bf0[jn][kk], acc[4 + im][jn], 0, 0, 0);
        __builtin_amdgcn_s_setprio(0);
        __builtin_amdgcn_s_barrier();

        // ---------------- P4 ----------------
        // slot-cur A fully read (P3 lgkm0 + barrier) -> safe to overwrite
        if (kt < 62) STAGE_M(gA, lA, kt + 2, (kt & 1));
        __builtin_amdgcn_s_setprio(1);
#pragma unroll
        for (int im = 0; im < 4; ++im)
#pragma unroll
            for (int jn = 0; jn < 2; ++jn)
#pragma unroll
                for (int kk = 0; kk < 2; ++kk)
                    acc[4 + im][2 + jn] = __builtin_amdgcn_mfma_f32_16x16x32_bf16(
                        af[im][kk], bf1[jn][kk], acc[4 + im][2 + jn], 0, 0, 0);
        __builtin_amdgcn_s_setprio(0);
        if (kt < 62) {
            asm volatile("s_waitcnt vmcnt(8)" ::: "memory");  // K-tile kt+1 landed
        } else {
            asm volatile("s_waitcnt vmcnt(0)" ::: "memory");  // drain tail
        }
        __builtin_amdgcn_s_barrier();
    }

    // epilogue: C/D layout col = lane&15, row = (lane>>4)*4 + reg
    const int crow = m0 + wr * 128 + ((lane >> 4) << 2);
    const int ccol = n0 + wc * 64 + l15;
#pragma unroll
    for (int im = 0; im < 8; ++im)
#pragma unroll
        for (int jn = 0; jn < 4; ++jn)
#pragma unroll
            for (int r = 0; r < 4; ++r)
                C[(size_t)(crow + im * 16 + r) * N_OUT + ccol + jn * 16] =
                    acc[im][jn][r];
}

extern "C" void kernel_launch(void* const* d_in, const int* in_sizes, int n_in,
                              void* d_out, int out_size, void* d_ws, size_t ws_size,
                              hipStream_t stream) {
    const float* x    = (const float*)d_in[0];   // [2,2048,4096] fp32
    const float* data = (const float*)d_in[1];   // [NNZ]
    const int*   rows = (const int*)d_in[2];
    const int*   cols = (const int*)d_in[3];
    float*       out  = (float*)d_out;           // [2,2048,4096] fp32

    // workspace layout:
    //   W_bf16  32 MiB @ 0
    //   x_bf16  32 MiB @ 32M
    //   run    ~6.7 MiB @ 64M  (128 blocks x 13108 x 4B, bin-sorted per block)
    //   Fbase  ~257 KiB @ 72M  ((NBINS+1) x 128 x 4B, transposed [bin][blk])
    unsigned short* W_bf16 = (unsigned short*)d_ws;
    unsigned short* x_bf16 = (unsigned short*)((char*)d_ws + (32u << 20));
    uint32_t*       run    = (uint32_t*)((char*)d_ws + (64u << 20));
    uint32_t*       Fbase  = (uint32_t*)((char*)d_ws + (72u << 20));

    // 1. convert x -> bf16 (16.7M elems, 8/thread)
    convert_x<<<(M_ROWS * K_IN) / (8 * 256), 256, 0, stream>>>(
        (const float4*)x, (uint4*)x_bf16);

    // 2. block-local counting sort (all scatter in LDS; global I/O coalesced)
    sort_local<<<NBLK_A, 1024, 0, stream>>>(data, rows, cols, run, Fbase);

    // 3. per-8-row-bin accumulate -> dense bf16 W (absorbs W zeroing)
    accum_bins<<<NBINS, 512, 0, stream>>>(run, Fbase, W_bf16);

    // 4. y = x * W^T via bf16 MFMA GEMM (256x256 tile, 8-wave phase-split)
    dim3 grid(N_OUT / 256, M_ROWS / 256);  // 16 x 16 = 256 blocks = 1/CU
    gemm_bt<<<grid, 512, 0, stream>>>(x_bf16, W_bf16, out);
}